// Round 25
// baseline (61.586 us; speedup 1.0000x reference)
//
#include <hip/hip_runtime.h>

#define M_ROWS 16384
#define DIMX   1024
#define CD     12
#define KCB    4096
#define PADW   52   // 48 data + 4 pad dwords: 53.25 KB LDS; conflict-free b128
#define NSLAB  512  // one hist slab per k_body block

// ---------- Kernel A: h = x @ W_in + b_in ; writes h and oidx ----------
// Round-17 proven version verbatim: grid 256, 512 threads, 8 rows per wave,
// folded butterfly (bit-identical tree => exact indices). Rounds 13/18/19/23/24
// established: 2-row/W-sweep + this grid is the register-feasible optimum.
__global__ __launch_bounds__(512) void k_hproj(
    const float* __restrict__ x, const float* __restrict__ Win,
    const float* __restrict__ bin, float* __restrict__ h, float* __restrict__ oidx)
{
  __shared__ __align__(16) float w[256 * PADW];   // 53.25 KB
  for (int f = threadIdx.x; f < 256 * 12; f += 512) {
    const int P = f / 12, c = f % 12;
    float4 v4 = reinterpret_cast<const float4*>(Win)[f];
    *reinterpret_cast<float4*>(&w[P * PADW + 4 * c]) = v4;
  }
  __syncthreads();

  const int wave = threadIdx.x >> 6;              // 0..7
  const int lane = threadIdx.x & 63;
  const int g    = blockIdx.x * 8 + wave;         // 8 rows per wave

  const float mybin = bin[lane < 12 ? lane : (lane < 24 ? lane - 12 : 0)];

  for (int it = 0; it < 4; ++it) {                // 2 rows per iteration
    const int row0 = g * 8 + it * 2;
    const float4* xr0 = reinterpret_cast<const float4*>(x + (size_t)row0 * DIMX);
    const float4* xr1 = reinterpret_cast<const float4*>(x + (size_t)(row0 + 1) * DIMX);
    float a0[CD], a1[CD];
#pragma unroll
    for (int d = 0; d < CD; ++d) { a0[d] = 0.f; a1[d] = 0.f; }

#pragma unroll
    for (int k = 0; k < 4; ++k) {
      const int P = lane + 64 * k;
      float4 xv0 = xr0[P];
      float4 xv1 = xr1[P];
      const float4* wf = reinterpret_cast<const float4*>(&w[P * PADW]);
      float4 wq[12];
#pragma unroll
      for (int c = 0; c < 12; ++c) wq[c] = wf[c];
      const float* wfl = reinterpret_cast<const float*>(wq);
      float xe0[4] = {xv0.x, xv0.y, xv0.z, xv0.w};
      float xe1[4] = {xv1.x, xv1.y, xv1.z, xv1.w};
#pragma unroll
      for (int e = 0; e < 4; ++e)
#pragma unroll
        for (int d = 0; d < CD; ++d) {
          const float wv = wfl[e * CD + d];
          a0[d] = fmaf(xe0[e], wv, a0[d]);
          a1[d] = fmaf(xe1[e], wv, a1[d]);
        }
    }

    // ---- folded butterfly (bit-identical tree: a[l] + a[l^D], D=1,2,4,8,16,32) ----
    float v[24];
#pragma unroll
    for (int d = 0; d < CD; ++d) { v[d] = a0[d]; v[12 + d] = a1[d]; }
#pragma unroll
    for (int i = 0; i < 12; ++i) {
      const float A = v[2 * i], B = v[2 * i + 1];
      const float keep = (lane & 1) ? B : A;
      const float give = (lane & 1) ? A : B;
      v[i] = keep + __shfl_xor(give, 1, 64);
    }
#pragma unroll
    for (int i = 0; i < 6; ++i) {
      const float A = v[2 * i], B = v[2 * i + 1];
      const float keep = (lane & 2) ? B : A;
      const float give = (lane & 2) ? A : B;
      v[i] = keep + __shfl_xor(give, 2, 64);
    }
#pragma unroll
    for (int i = 0; i < 3; ++i) {
      const float A = v[2 * i], B = v[2 * i + 1];
      const float keep = (lane & 4) ? B : A;
      const float give = (lane & 4) ? A : B;
      v[i] = keep + __shfl_xor(give, 4, 64);
    }
    {
      const float A = v[0], B = v[1];
      const float keep = (lane & 8) ? B : A;
      const float give = (lane & 8) ? A : B;
      v[0] = keep + __shfl_xor(give, 8, 64);
      v[1] = v[2] + __shfl_xor(v[2], 8, 64);
    }
    {
      const float A = v[0], B = v[1];
      const float keep = (lane & 16) ? B : A;
      const float give = (lane & 16) ? A : B;
      v[0] = keep + __shfl_xor(give, 16, 64);
    }
    v[0] += __shfl_xor(v[0], 32, 64);

    const float hv = v[0] + mybin;
    const unsigned long long mask = __ballot(hv > 0.f);
    if (lane < 24) h[(size_t)row0 * CD + lane] = hv;
    if (lane == 0) {
      oidx[row0]     = (float)((int)(mask & 0xFFFULL));
      oidx[row0 + 1] = (float)((int)((mask >> 12) & 0xFFFULL));
    }
  }
}

// ---------- Kernel B: fused out-projection + entropy/commit + histogram ----------
// Round-22 version verbatim (row-uniform precompute: signs, A4/A2/CDw tables).
__global__ __launch_bounds__(512) void k_body(
    const float* __restrict__ h, const float* __restrict__ Wout,
    const float* __restrict__ bout, float* __restrict__ out,
    float* __restrict__ hist_part, float* __restrict__ scal_part)
{
  __shared__ __align__(16) float sq[32 * 96];    // 12 KB
  __shared__ float pp[8], cc[8];
  const int t    = threadIdx.x;          // 0..511
  const int bid  = blockIdx.x;
  const int row0 = bid * 32;

  // ---------------- Phase 0a: sign + q-scratch per (row,d) ----------------
  if (t < 384) {                          // one (row,d) per thread
    const int row = t / 12, d = t % 12;
    const float hv  = h[(size_t)row0 * CD + t];   // coalesced 384 floats
    const float ax  = fabsf(40.f * hv);
    const float e2  = __expf(-ax);
    const float s1  = 1.f + e2;
    const float inv = 1.f / s1;
    const float qv  = (hv > 0.f) ? inv : e2 * inv;          // sigmoid(40 h)
    float* rb = &sq[row * 96];
    rb[d]      = (hv > 0.f) ? 1.f : -1.f;                    // sign
    rb[32 + d] = qv;                                         // q scratch
    float pse_c = __logf(s1) + ax * e2 * inv;                // per-dim entropy
    const float dd = fabsf(hv) - 1.f;
    float com_c = dd * dd;
#pragma unroll
    for (int ofs = 1; ofs < 64; ofs <<= 1) {
      pse_c += __shfl_xor(pse_c, ofs, 64);
      com_c += __shfl_xor(com_c, ofs, 64);
    }
    if ((t & 63) == 0) { pp[t >> 6] = pse_c; cc[t >> 6] = com_c; }
  }

  // W_out fragment + bias (independent of LDS)
  float w0[CD], w1[CD];
#pragma unroll
  for (int d = 0; d < CD; ++d) {
    float2 v = *reinterpret_cast<const float2*>(Wout + d * DIMX + 2 * t);
    w0[d] = v.x; w1[d] = v.y;
  }
  const float2 b2 = *reinterpret_cast<const float2*>(bout + 2 * t);

  __syncthreads();                        // signs + q written

  // ---------------- Phase 0b: A4/A2/CDw tables once per row ----------------
  if (t < 32) {
    float* rb = &sq[t * 96];
    float q[12];
#pragma unroll
    for (int d = 0; d < 12; ++d) q[d] = rb[32 + d];   // read BEFORE overwrite
    const float t0 = 1.f - q[0], t1 = 1.f - q[1], t2 = 1.f - q[2], t3 = 1.f - q[3];
    const float t4 = 1.f - q[4], t5 = 1.f - q[5];
    float b0 = t0 * t1, b1 = q[0] * t1, b2_ = t0 * q[1], b3 = q[0] * q[1];
    float cc0 = b0 * t2, cc1 = b1 * t2, cc2 = b2_ * t2, cc3 = b3 * t2;
    float cc4 = b0 * q[2], cc5 = b1 * q[2], cc6 = b2_ * q[2], cc7 = b3 * q[2];
    rb[12]  = cc0 * t3;  rb[13] = cc1 * t3;  rb[14] = cc2 * t3;  rb[15] = cc3 * t3;
    rb[16]  = cc4 * t3;  rb[17] = cc5 * t3;  rb[18] = cc6 * t3;  rb[19] = cc7 * t3;
    rb[20]  = cc0 * q[3]; rb[21] = cc1 * q[3]; rb[22] = cc2 * q[3]; rb[23] = cc3 * q[3];
    rb[24]  = cc4 * q[3]; rb[25] = cc5 * q[3]; rb[26] = cc6 * q[3]; rb[27] = cc7 * q[3];
    rb[28] = t4 * t5; rb[29] = q[4] * t5; rb[30] = t4 * q[5]; rb[31] = q[4] * q[5];
    const float t6 = 1.f - q[6], t7 = 1.f - q[7], t8 = 1.f - q[8];
    const float u0 = t6 * t7, u1 = q[6] * t7, u2 = t6 * q[7], u3 = q[6] * q[7];
    float C[8];
    C[0] = u0 * t8;   C[1] = u1 * t8;   C[2] = u2 * t8;   C[3] = u3 * t8;
    C[4] = u0 * q[8]; C[5] = u1 * q[8]; C[6] = u2 * q[8]; C[7] = u3 * q[8];
    const float t9 = 1.f - q[9], t10 = 1.f - q[10], t11 = 1.f - q[11];
    const float p0 = t9 * t10, p1 = q[9] * t10, p2 = t9 * q[10], p3 = q[9] * q[10];
    float D[8];
    D[0] = p0 * t11;   D[1] = p1 * t11;   D[2] = p2 * t11;   D[3] = p3 * t11;
    D[4] = p0 * q[11]; D[5] = p1 * q[11]; D[6] = p2 * q[11]; D[7] = p3 * q[11];
#pragma unroll
    for (int wv = 0; wv < 8; ++wv)
#pragma unroll
      for (int e = 0; e < 8; ++e)
        rb[32 + wv * 8 + e] = C[e] * D[wv];
  }

  __syncthreads();                        // row records complete

  // ---------------- Fused per-row loop: out-write + histogram ----------------
  const int lane = t & 63;
  const int w8   = t >> 6;                // wave id 0..7; m in [8*w8, 8*w8+8)

  float c0=0.f,c1=0.f,c2=0.f,c3=0.f,c4=0.f,c5=0.f,c6=0.f,c7=0.f;

  for (int i = 0; i < 32; ++i) {
    const float* rb = &sq[i * 96];
    const float4 s03  = *reinterpret_cast<const float4*>(rb);
    const float4 s47  = *reinterpret_cast<const float4*>(rb + 4);
    const float4 s811 = *reinterpret_cast<const float4*>(rb + 8);
    const float  A4v  = rb[12 + (lane & 15)];
    const float  A2v  = rb[28 + (lane >> 4)];
    const float4 CD03 = *reinterpret_cast<const float4*>(rb + 32 + w8 * 8);
    const float4 CD47 = *reinterpret_cast<const float4*>(rb + 36 + w8 * 8);

    float o0 = b2.x, o1 = b2.y;
    o0 = fmaf(s03.x,  w0[0],  o0); o1 = fmaf(s03.x,  w1[0],  o1);
    o0 = fmaf(s03.y,  w0[1],  o0); o1 = fmaf(s03.y,  w1[1],  o1);
    o0 = fmaf(s03.z,  w0[2],  o0); o1 = fmaf(s03.z,  w1[2],  o1);
    o0 = fmaf(s03.w,  w0[3],  o0); o1 = fmaf(s03.w,  w1[3],  o1);
    o0 = fmaf(s47.x,  w0[4],  o0); o1 = fmaf(s47.x,  w1[4],  o1);
    o0 = fmaf(s47.y,  w0[5],  o0); o1 = fmaf(s47.y,  w1[5],  o1);
    o0 = fmaf(s47.z,  w0[6],  o0); o1 = fmaf(s47.z,  w1[6],  o1);
    o0 = fmaf(s47.w,  w0[7],  o0); o1 = fmaf(s47.w,  w1[7],  o1);
    o0 = fmaf(s811.x, w0[8],  o0); o1 = fmaf(s811.x, w1[8],  o1);
    o0 = fmaf(s811.y, w0[9],  o0); o1 = fmaf(s811.y, w1[9],  o1);
    o0 = fmaf(s811.z, w0[10], o0); o1 = fmaf(s811.z, w1[10], o1);
    o0 = fmaf(s811.w, w0[11], o0); o1 = fmaf(s811.w, w1[11], o1);
    *reinterpret_cast<float2*>(out + (size_t)(row0 + i) * DIMX + 2 * t)
        = make_float2(o0, o1);

    const float A = A4v * A2v;
    c0 = fmaf(A, CD03.x, c0); c1 = fmaf(A, CD03.y, c1);
    c2 = fmaf(A, CD03.z, c2); c3 = fmaf(A, CD03.w, c3);
    c4 = fmaf(A, CD47.x, c4); c5 = fmaf(A, CD47.y, c5);
    c6 = fmaf(A, CD47.z, c6); c7 = fmaf(A, CD47.w, c7);
  }

  // disjoint coalesced slab write: index = (8*w8 + e)*64 + lane
  float* hp = hist_part + (size_t)bid * KCB + (size_t)w8 * 512 + lane;
  hp[0*64] = c0; hp[1*64] = c1; hp[2*64] = c2; hp[3*64] = c3;
  hp[4*64] = c4; hp[5*64] = c5; hp[6*64] = c6; hp[7*64] = c7;

  // tail: plain per-block partial stores (no atomics, nothing pre-zeroed)
  if (t == 0) {
    scal_part[bid * 2]     = pp[0] + pp[1] + pp[2] + pp[3] + pp[4] + pp[5];
    scal_part[bid * 2 + 1] = cc[0] + cc[1] + cc[2] + cc[3] + cc[4] + cc[5];
  }
}

// ---------- Kernel C: stage-1 slab reduction (ROUND-25: 256 blocks, 32 chunks) ----------
__global__ __launch_bounds__(256) void k_hr1(
    const float* __restrict__ hist_part, float* __restrict__ part2)
{
  const int j0    = (blockIdx.x & 7) * 512 + threadIdx.x;
  const int chunk = blockIdx.x >> 3;              // 0..31
  const int s0    = chunk * (NSLAB / 32);         // 16 slabs per chunk
  float acc0 = 0.f, acc1 = 0.f;
#pragma unroll 4
  for (int s = 0; s < NSLAB / 32; ++s) {
    const float* hp = hist_part + (size_t)(s0 + s) * KCB;
    acc0 += hp[j0];
    acc1 += hp[j0 + 256];
  }
  part2[(size_t)chunk * KCB + j0]       = acc0;
  part2[(size_t)chunk * KCB + j0 + 256] = acc1;
}

// ---------- Kernel D: final entropy + scalar partials -> aux (1 block) ----------
__global__ __launch_bounds__(256) void k_fin(
    const float* __restrict__ part2, const float* __restrict__ scal_part,
    float* __restrict__ aux)
{
  const int t = threadIdx.x;
  float term = 0.f;
#pragma unroll
  for (int k = 0; k < 16; ++k) {
    const int j = t + 256 * k;
    float a = 0.f;
#pragma unroll
    for (int c = 0; c < 32; ++c) a += part2[(size_t)c * KCB + j];
    a *= (1.f / 16384.f);
    term -= a * __logf(a + 1e-10f);
  }
  // pse/com partials: 512 blocks x {pse, com}
  const float2 s0 = *reinterpret_cast<const float2*>(&scal_part[2 * t]);
  const float2 s1 = *reinterpret_cast<const float2*>(&scal_part[2 * (t + 256)]);
  float ps = s0.x + s1.x;
  float cs = s0.y + s1.y;
#pragma unroll
  for (int ofs = 1; ofs < 64; ofs <<= 1) {
    term += __shfl_xor(term, ofs, 64);
    ps   += __shfl_xor(ps,   ofs, 64);
    cs   += __shfl_xor(cs,   ofs, 64);
  }
  __shared__ float sw[4], sp[4], sc[4];
  if ((t & 63) == 0) { sw[t >> 6] = term; sp[t >> 6] = ps; sc[t >> 6] = cs; }
  __syncthreads();
  if (t == 0) {
    const float cbe = sw[0] + sw[1] + sw[2] + sw[3];
    const float PS  = sp[0] + sp[1] + sp[2] + sp[3];
    const float CS  = sc[0] + sc[1] + sc[2] + sc[3];
    aux[0] = PS * (1.f / 16384.f) - cbe + CS * (1.f / 196608.f);
  }
}

extern "C" void kernel_launch(void* const* d_in, const int* in_sizes, int n_in,
                              void* d_out, int out_size, void* d_ws, size_t ws_size,
                              hipStream_t stream)
{
  const float* x    = (const float*)d_in[0];
  const float* Win  = (const float*)d_in[1];
  const float* bin  = (const float*)d_in[2];
  const float* Wout = (const float*)d_in[3];
  const float* bout = (const float*)d_in[4];

  float* out  = (float*)d_out;                       // [16384 x 1024]
  float* oidx = out + (size_t)M_ROWS * DIMX;         // [16384]
  float* aux  = oidx + M_ROWS;                       // [1]

  float* ws        = (float*)d_ws;
  float* h         = ws;                             // 196608 floats
  float* scal_part = ws + (size_t)M_ROWS * CD;       // 1024 floats
  float* part2     = scal_part + 1024;               // 32 * 4096 floats
  float* hist_part = part2 + 32 * KCB;               // NSLAB * 4096 floats

  k_hproj<<<256, 512, 0, stream>>>(x, Win, bin, h, oidx);
  k_body <<<NSLAB, 512, 0, stream>>>(h, Wout, bout, out, hist_part, scal_part);
  k_hr1  <<<256, 256, 0, stream>>>(hist_part, part2);
  k_fin  <<<1, 256, 0, stream>>>(part2, scal_part, aux);
}

// Round 26
// 45.987 us; speedup vs baseline: 1.3392x; 1.3392x over previous
//
#include <hip/hip_runtime.h>

#define M_ROWS 16384
#define DIMX   1024
#define CD     12
#define KCB    4096
#define PADW   52   // 48 data + 4 pad dwords: 53.25 KB LDS; conflict-free b128
#define NSLAB  512  // one hist slab per k_body block

// ---------- Kernel A: h = x @ W_in + b_in ; writes h and oidx ----------
// Round-17 proven version verbatim: grid 256, 512 threads, 8 rows per wave,
// folded butterfly (bit-identical tree => exact indices).
__global__ __launch_bounds__(512) void k_hproj(
    const float* __restrict__ x, const float* __restrict__ Win,
    const float* __restrict__ bin, float* __restrict__ h, float* __restrict__ oidx)
{
  __shared__ __align__(16) float w[256 * PADW];   // 53.25 KB
  for (int f = threadIdx.x; f < 256 * 12; f += 512) {
    const int P = f / 12, c = f % 12;
    float4 v4 = reinterpret_cast<const float4*>(Win)[f];
    *reinterpret_cast<float4*>(&w[P * PADW + 4 * c]) = v4;
  }
  __syncthreads();

  const int wave = threadIdx.x >> 6;              // 0..7
  const int lane = threadIdx.x & 63;
  const int g    = blockIdx.x * 8 + wave;         // 8 rows per wave

  const float mybin = bin[lane < 12 ? lane : (lane < 24 ? lane - 12 : 0)];

  for (int it = 0; it < 4; ++it) {                // 2 rows per iteration
    const int row0 = g * 8 + it * 2;
    const float4* xr0 = reinterpret_cast<const float4*>(x + (size_t)row0 * DIMX);
    const float4* xr1 = reinterpret_cast<const float4*>(x + (size_t)(row0 + 1) * DIMX);
    float a0[CD], a1[CD];
#pragma unroll
    for (int d = 0; d < CD; ++d) { a0[d] = 0.f; a1[d] = 0.f; }

#pragma unroll
    for (int k = 0; k < 4; ++k) {
      const int P = lane + 64 * k;
      float4 xv0 = xr0[P];
      float4 xv1 = xr1[P];
      const float4* wf = reinterpret_cast<const float4*>(&w[P * PADW]);
      float4 wq[12];
#pragma unroll
      for (int c = 0; c < 12; ++c) wq[c] = wf[c];
      const float* wfl = reinterpret_cast<const float*>(wq);
      float xe0[4] = {xv0.x, xv0.y, xv0.z, xv0.w};
      float xe1[4] = {xv1.x, xv1.y, xv1.z, xv1.w};
#pragma unroll
      for (int e = 0; e < 4; ++e)
#pragma unroll
        for (int d = 0; d < CD; ++d) {
          const float wv = wfl[e * CD + d];
          a0[d] = fmaf(xe0[e], wv, a0[d]);
          a1[d] = fmaf(xe1[e], wv, a1[d]);
        }
    }

    // ---- folded butterfly (bit-identical tree: a[l] + a[l^D], D=1,2,4,8,16,32) ----
    float v[24];
#pragma unroll
    for (int d = 0; d < CD; ++d) { v[d] = a0[d]; v[12 + d] = a1[d]; }
#pragma unroll
    for (int i = 0; i < 12; ++i) {
      const float A = v[2 * i], B = v[2 * i + 1];
      const float keep = (lane & 1) ? B : A;
      const float give = (lane & 1) ? A : B;
      v[i] = keep + __shfl_xor(give, 1, 64);
    }
#pragma unroll
    for (int i = 0; i < 6; ++i) {
      const float A = v[2 * i], B = v[2 * i + 1];
      const float keep = (lane & 2) ? B : A;
      const float give = (lane & 2) ? A : B;
      v[i] = keep + __shfl_xor(give, 2, 64);
    }
#pragma unroll
    for (int i = 0; i < 3; ++i) {
      const float A = v[2 * i], B = v[2 * i + 1];
      const float keep = (lane & 4) ? B : A;
      const float give = (lane & 4) ? A : B;
      v[i] = keep + __shfl_xor(give, 4, 64);
    }
    {
      const float A = v[0], B = v[1];
      const float keep = (lane & 8) ? B : A;
      const float give = (lane & 8) ? A : B;
      v[0] = keep + __shfl_xor(give, 8, 64);
      v[1] = v[2] + __shfl_xor(v[2], 8, 64);
    }
    {
      const float A = v[0], B = v[1];
      const float keep = (lane & 16) ? B : A;
      const float give = (lane & 16) ? A : B;
      v[0] = keep + __shfl_xor(give, 16, 64);
    }
    v[0] += __shfl_xor(v[0], 32, 64);

    const float hv = v[0] + mybin;
    const unsigned long long mask = __ballot(hv > 0.f);
    if (lane < 24) h[(size_t)row0 * CD + lane] = hv;
    if (lane == 0) {
      oidx[row0]     = (float)((int)(mask & 0xFFFULL));
      oidx[row0 + 1] = (float)((int)((mask >> 12) & 0xFFFULL));
    }
  }
}

// ---------- Kernel B: fused out-projection + entropy/commit + histogram ----------
// Round-22 version verbatim (row-uniform precompute: signs, A4/A2/CDw tables).
__global__ __launch_bounds__(512) void k_body(
    const float* __restrict__ h, const float* __restrict__ Wout,
    const float* __restrict__ bout, float* __restrict__ out,
    float* __restrict__ hist_part, float* __restrict__ scal_part)
{
  __shared__ __align__(16) float sq[32 * 96];    // 12 KB
  __shared__ float pp[8], cc[8];
  const int t    = threadIdx.x;          // 0..511
  const int bid  = blockIdx.x;
  const int row0 = bid * 32;

  // ---------------- Phase 0a: sign + q-scratch per (row,d) ----------------
  if (t < 384) {                          // one (row,d) per thread
    const int row = t / 12, d = t % 12;
    const float hv  = h[(size_t)row0 * CD + t];   // coalesced 384 floats
    const float ax  = fabsf(40.f * hv);
    const float e2  = __expf(-ax);
    const float s1  = 1.f + e2;
    const float inv = 1.f / s1;
    const float qv  = (hv > 0.f) ? inv : e2 * inv;          // sigmoid(40 h)
    float* rb = &sq[row * 96];
    rb[d]      = (hv > 0.f) ? 1.f : -1.f;                    // sign
    rb[32 + d] = qv;                                         // q scratch
    float pse_c = __logf(s1) + ax * e2 * inv;                // per-dim entropy
    const float dd = fabsf(hv) - 1.f;
    float com_c = dd * dd;
#pragma unroll
    for (int ofs = 1; ofs < 64; ofs <<= 1) {
      pse_c += __shfl_xor(pse_c, ofs, 64);
      com_c += __shfl_xor(com_c, ofs, 64);
    }
    if ((t & 63) == 0) { pp[t >> 6] = pse_c; cc[t >> 6] = com_c; }
  }

  // W_out fragment + bias (independent of LDS)
  float w0[CD], w1[CD];
#pragma unroll
  for (int d = 0; d < CD; ++d) {
    float2 v = *reinterpret_cast<const float2*>(Wout + d * DIMX + 2 * t);
    w0[d] = v.x; w1[d] = v.y;
  }
  const float2 b2 = *reinterpret_cast<const float2*>(bout + 2 * t);

  __syncthreads();                        // signs + q written

  // ---------------- Phase 0b: A4/A2/CDw tables once per row ----------------
  if (t < 32) {
    float* rb = &sq[t * 96];
    float q[12];
#pragma unroll
    for (int d = 0; d < 12; ++d) q[d] = rb[32 + d];   // read BEFORE overwrite
    const float t0 = 1.f - q[0], t1 = 1.f - q[1], t2 = 1.f - q[2], t3 = 1.f - q[3];
    const float t4 = 1.f - q[4], t5 = 1.f - q[5];
    float b0 = t0 * t1, b1 = q[0] * t1, b2_ = t0 * q[1], b3 = q[0] * q[1];
    float cc0 = b0 * t2, cc1 = b1 * t2, cc2 = b2_ * t2, cc3 = b3 * t2;
    float cc4 = b0 * q[2], cc5 = b1 * q[2], cc6 = b2_ * q[2], cc7 = b3 * q[2];
    rb[12]  = cc0 * t3;  rb[13] = cc1 * t3;  rb[14] = cc2 * t3;  rb[15] = cc3 * t3;
    rb[16]  = cc4 * t3;  rb[17] = cc5 * t3;  rb[18] = cc6 * t3;  rb[19] = cc7 * t3;
    rb[20]  = cc0 * q[3]; rb[21] = cc1 * q[3]; rb[22] = cc2 * q[3]; rb[23] = cc3 * q[3];
    rb[24]  = cc4 * q[3]; rb[25] = cc5 * q[3]; rb[26] = cc6 * q[3]; rb[27] = cc7 * q[3];
    rb[28] = t4 * t5; rb[29] = q[4] * t5; rb[30] = t4 * q[5]; rb[31] = q[4] * q[5];
    const float t6 = 1.f - q[6], t7 = 1.f - q[7], t8 = 1.f - q[8];
    const float u0 = t6 * t7, u1 = q[6] * t7, u2 = t6 * q[7], u3 = q[6] * q[7];
    float C[8];
    C[0] = u0 * t8;   C[1] = u1 * t8;   C[2] = u2 * t8;   C[3] = u3 * t8;
    C[4] = u0 * q[8]; C[5] = u1 * q[8]; C[6] = u2 * q[8]; C[7] = u3 * q[8];
    const float t9 = 1.f - q[9], t10 = 1.f - q[10], t11 = 1.f - q[11];
    const float p0 = t9 * t10, p1 = q[9] * t10, p2 = t9 * q[10], p3 = q[9] * q[10];
    float D[8];
    D[0] = p0 * t11;   D[1] = p1 * t11;   D[2] = p2 * t11;   D[3] = p3 * t11;
    D[4] = p0 * q[11]; D[5] = p1 * q[11]; D[6] = p2 * q[11]; D[7] = p3 * q[11];
#pragma unroll
    for (int wv = 0; wv < 8; ++wv)
#pragma unroll
      for (int e = 0; e < 8; ++e)
        rb[32 + wv * 8 + e] = C[e] * D[wv];
  }

  __syncthreads();                        // row records complete

  // ---------------- Fused per-row loop: out-write + histogram ----------------
  const int lane = t & 63;
  const int w8   = t >> 6;                // wave id 0..7; m in [8*w8, 8*w8+8)

  float c0=0.f,c1=0.f,c2=0.f,c3=0.f,c4=0.f,c5=0.f,c6=0.f,c7=0.f;

  for (int i = 0; i < 32; ++i) {
    const float* rb = &sq[i * 96];
    const float4 s03  = *reinterpret_cast<const float4*>(rb);
    const float4 s47  = *reinterpret_cast<const float4*>(rb + 4);
    const float4 s811 = *reinterpret_cast<const float4*>(rb + 8);
    const float  A4v  = rb[12 + (lane & 15)];
    const float  A2v  = rb[28 + (lane >> 4)];
    const float4 CD03 = *reinterpret_cast<const float4*>(rb + 32 + w8 * 8);
    const float4 CD47 = *reinterpret_cast<const float4*>(rb + 36 + w8 * 8);

    float o0 = b2.x, o1 = b2.y;
    o0 = fmaf(s03.x,  w0[0],  o0); o1 = fmaf(s03.x,  w1[0],  o1);
    o0 = fmaf(s03.y,  w0[1],  o0); o1 = fmaf(s03.y,  w1[1],  o1);
    o0 = fmaf(s03.z,  w0[2],  o0); o1 = fmaf(s03.z,  w1[2],  o1);
    o0 = fmaf(s03.w,  w0[3],  o0); o1 = fmaf(s03.w,  w1[3],  o1);
    o0 = fmaf(s47.x,  w0[4],  o0); o1 = fmaf(s47.x,  w1[4],  o1);
    o0 = fmaf(s47.y,  w0[5],  o0); o1 = fmaf(s47.y,  w1[5],  o1);
    o0 = fmaf(s47.z,  w0[6],  o0); o1 = fmaf(s47.z,  w1[6],  o1);
    o0 = fmaf(s47.w,  w0[7],  o0); o1 = fmaf(s47.w,  w1[7],  o1);
    o0 = fmaf(s811.x, w0[8],  o0); o1 = fmaf(s811.x, w1[8],  o1);
    o0 = fmaf(s811.y, w0[9],  o0); o1 = fmaf(s811.y, w1[9],  o1);
    o0 = fmaf(s811.z, w0[10], o0); o1 = fmaf(s811.z, w1[10], o1);
    o0 = fmaf(s811.w, w0[11], o0); o1 = fmaf(s811.w, w1[11], o1);
    *reinterpret_cast<float2*>(out + (size_t)(row0 + i) * DIMX + 2 * t)
        = make_float2(o0, o1);

    const float A = A4v * A2v;
    c0 = fmaf(A, CD03.x, c0); c1 = fmaf(A, CD03.y, c1);
    c2 = fmaf(A, CD03.z, c2); c3 = fmaf(A, CD03.w, c3);
    c4 = fmaf(A, CD47.x, c4); c5 = fmaf(A, CD47.y, c5);
    c6 = fmaf(A, CD47.z, c6); c7 = fmaf(A, CD47.w, c7);
  }

  // disjoint coalesced slab write: index = (8*w8 + e)*64 + lane
  float* hp = hist_part + (size_t)bid * KCB + (size_t)w8 * 512 + lane;
  hp[0*64] = c0; hp[1*64] = c1; hp[2*64] = c2; hp[3*64] = c3;
  hp[4*64] = c4; hp[5*64] = c5; hp[6*64] = c6; hp[7*64] = c7;

  // tail: plain per-block partial stores (no atomics, nothing pre-zeroed)
  if (t == 0) {
    scal_part[bid * 2]     = pp[0] + pp[1] + pp[2] + pp[3] + pp[4] + pp[5];
    scal_part[bid * 2 + 1] = cc[0] + cc[1] + cc[2] + cc[3] + cc[4] + cc[5];
  }
}

// ---------- Kernel C: stage-1 slab reduction (128 blocks) ----------
__global__ __launch_bounds__(256) void k_hr1(
    const float* __restrict__ hist_part, float* __restrict__ part2)
{
  const int j0    = (blockIdx.x & 7) * 512 + threadIdx.x;
  const int chunk = blockIdx.x >> 3;              // 0..15
  const int s0    = chunk * (NSLAB / 16);
  float acc0 = 0.f, acc1 = 0.f;
#pragma unroll 4
  for (int s = 0; s < NSLAB / 16; ++s) {
    const float* hp = hist_part + (size_t)(s0 + s) * KCB;
    acc0 += hp[j0];
    acc1 += hp[j0 + 256];
  }
  part2[(size_t)chunk * KCB + j0]       = acc0;
  part2[(size_t)chunk * KCB + j0 + 256] = acc1;
}

// ---------- Kernel D: final entropy + scalar partials -> aux (1 block) ----------
__global__ __launch_bounds__(256) void k_fin(
    const float* __restrict__ part2, const float* __restrict__ scal_part,
    float* __restrict__ aux)
{
  const int t = threadIdx.x;
  float term = 0.f;
#pragma unroll
  for (int k = 0; k < 16; ++k) {
    const int j = t + 256 * k;
    float a = 0.f;
#pragma unroll
    for (int c = 0; c < 16; ++c) a += part2[(size_t)c * KCB + j];
    a *= (1.f / 16384.f);
    term -= a * __logf(a + 1e-10f);
  }
  // pse/com partials: 512 blocks x {pse, com}
  const float2 s0 = *reinterpret_cast<const float2*>(&scal_part[2 * t]);
  const float2 s1 = *reinterpret_cast<const float2*>(&scal_part[2 * (t + 256)]);
  float ps = s0.x + s1.x;
  float cs = s0.y + s1.y;
#pragma unroll
  for (int ofs = 1; ofs < 64; ofs <<= 1) {
    term += __shfl_xor(term, ofs, 64);
    ps   += __shfl_xor(ps,   ofs, 64);
    cs   += __shfl_xor(cs,   ofs, 64);
  }
  __shared__ float sw[4], sp[4], sc[4];
  if ((t & 63) == 0) { sw[t >> 6] = term; sp[t >> 6] = ps; sc[t >> 6] = cs; }
  __syncthreads();
  if (t == 0) {
    const float cbe = sw[0] + sw[1] + sw[2] + sw[3];
    const float PS  = sp[0] + sp[1] + sp[2] + sp[3];
    const float CS  = sc[0] + sc[1] + sc[2] + sc[3];
    aux[0] = PS * (1.f / 16384.f) - cbe + CS * (1.f / 196608.f);
  }
}

extern "C" void kernel_launch(void* const* d_in, const int* in_sizes, int n_in,
                              void* d_out, int out_size, void* d_ws, size_t ws_size,
                              hipStream_t stream)
{
  const float* x    = (const float*)d_in[0];
  const float* Win  = (const float*)d_in[1];
  const float* bin  = (const float*)d_in[2];
  const float* Wout = (const float*)d_in[3];
  const float* bout = (const float*)d_in[4];

  float* out  = (float*)d_out;                       // [16384 x 1024]
  float* oidx = out + (size_t)M_ROWS * DIMX;         // [16384]
  float* aux  = oidx + M_ROWS;                       // [1]

  float* ws        = (float*)d_ws;
  float* h         = ws;                             // 196608 floats
  float* scal_part = ws + (size_t)M_ROWS * CD;       // 1024 floats
  float* part2     = scal_part + 1024;               // 16 * 4096 floats
  float* hist_part = part2 + 16 * KCB;               // NSLAB * 4096 floats

  k_hproj<<<256, 512, 0, stream>>>(x, Win, bin, h, oidx);
  k_body <<<NSLAB, 512, 0, stream>>>(h, Wout, bout, out, hist_part, scal_part);
  k_hr1  <<<128, 256, 0, stream>>>(hist_part, part2);
  k_fin  <<<1, 256, 0, stream>>>(part2, scal_part, aux);
}